// Round 2
// baseline (57.912 us; speedup 1.0000x reference)
//
#include <hip/hip_runtime.h>
#include <hip/hip_bf16.h>

typedef __attribute__((ext_vector_type(8))) short bfrag;   // 8 bf16 = 4 VGPR
typedef __attribute__((ext_vector_type(4))) float vf4;     // 4 f32  accumulator

#define MFMA16(A,B,C) __builtin_amdgcn_mfma_f32_16x16x32_bf16(A,B,C,0,0,0)

struct KParams {
  const float* task; const float* hw; const int* mask;   // mask: bool -> int32 on harness side
  const float* te_w1; const float* te_b1; const float* te_w2; const float* te_b2;
  const float* he_w1; const float* he_b1; const float* he_w2; const float* he_b2;
  const float* sc_w1; const float* sc_b1; const float* sc_w2; const float* sc_b2;
  const float* sc_w3; const float* sc_b3;
  const float* rj_w1; const float* rj_b1; const float* rj_w2; const float* rj_b2;
  const float* vh_w1; const float* vh_b1; const float* vh_w2; const float* vh_b2;
  float* out; float* ws; int B;
};

__device__ __forceinline__ unsigned pack2(float a, float b){
  __hip_bfloat162 h = __float22bfloat162_rn(make_float2(a,b));
  unsigned u; __builtin_memcpy(&u, &h, 4); return u;
}

// Weight-fragment element: W^T tile (16 out-ch rows x 32 in-ch K), lane&15 = out-ch,
// K slot = q*32 + 16*(e>>2) + (lane>>4)*4 + (e&3). Same mapping used for activation
// packs => any true HW K-order gives correct dot products (bijection argument).
__device__ __forceinline__ float frag_elem(const KParams& P, int fid, int lane, int e){
  const float* W; const float* bias = nullptr; int OUT = 64, KREAL, c, q = 0;
  if (fid < 4)       { W=P.te_w1; bias=P.te_b1; KREAL=17; c=fid; }
  else if (fid < 12) { W=P.te_w2;              KREAL=64; int t=fid-4;  c=t>>1; q=t&1; }
  else if (fid < 20) { W=P.sc_w1;              KREAL=64; int t=fid-12; c=t>>1; q=t&1; }
  else if (fid < 28) { W=P.vh_w1;              KREAL=64; int t=fid-20; c=t>>1; q=t&1; }
  else if (fid < 32) { W=P.rj_w1; OUT=32;      KREAL=64; int t=fid-28; c=t>>1; q=t&1; }
  else if (fid < 36) { W=P.he_w1; bias=P.he_b1; KREAL=16; c=fid-32; }
  else if (fid < 44) { W=P.he_w2;              KREAL=64; int t=fid-36; c=t>>1; q=t&1; }
  else if (fid < 52) { W=P.sc_w1 + 64*64;      KREAL=64; int t=fid-44; c=t>>1; q=t&1; }
  else if (fid < 56) { W=P.sc_w2; OUT=32;      KREAL=64; int t=fid-52; c=t>>1; q=t&1; }
  else               { W=P.vh_w1 + 64*64;      KREAL=64; int t=fid-56; c=t>>1; q=t&1; }
  int row = c*16 + (lane & 15);
  int k   = q*32 + ((e>>2)<<4) + ((lane>>4)<<2) + (e&3);
  if (k < KREAL) return W[k*OUT + row];
  if (k == KREAL && bias) return bias[row];   // bias folded as extra K row
  return 0.f;
}

// Bias/vector chunks for MFMA C-init / epilogue dots: value = src[c*16 + (lane>>4)*4 + r]
__device__ __forceinline__ float chunk_elem(const KParams& P, int cid, int lane, int r){
  const float* src; int base;
  if (cid < 4)       { src=P.te_b2; base=cid*16; }
  else if (cid < 8)  { src=P.sc_b1; base=(cid-4)*16; }
  else if (cid < 12) { src=P.vh_b1; base=(cid-8)*16; }
  else if (cid < 14) { src=P.rj_b1; base=(cid-12)*16; }
  else if (cid < 18) { src=P.he_b2; base=(cid-14)*16; }
  else if (cid < 20) { src=P.sc_b2; base=(cid-18)*16; }
  else if (cid < 22) { src=P.sc_w3; base=(cid-20)*16; }
  else if (cid < 24) { src=P.rj_w2; base=(cid-22)*16; }
  else               { src=P.vh_w2; base=(cid-24)*16; }
  return src[base + ((lane>>4)<<2) + r];
}

// Pre-pack 64 weight frags (64 KB) + 28 chunks (28 KB) into ws, so main-kernel
// prologue is all coalesced dwordx4 loads.
__global__ void setup_frags(KParams P){
  int l = threadIdx.x, bid = blockIdx.x;
  if (bid < 64){
    uint4 u;
    u.x = pack2(frag_elem(P,bid,l,0), frag_elem(P,bid,l,1));
    u.y = pack2(frag_elem(P,bid,l,2), frag_elem(P,bid,l,3));
    u.z = pack2(frag_elem(P,bid,l,4), frag_elem(P,bid,l,5));
    u.w = pack2(frag_elem(P,bid,l,6), frag_elem(P,bid,l,7));
    ((uint4*)P.ws)[bid*64 + l] = u;
  } else {
    int cid = bid - 64;
    float4 v;
    v.x = chunk_elem(P,cid,l,0); v.y = chunk_elem(P,cid,l,1);
    v.z = chunk_elem(P,cid,l,2); v.w = chunk_elem(P,cid,l,3);
    ((float4*)(P.ws + 16384))[cid*64 + l] = v;
  }
}

template<int WS>
__device__ __forceinline__ bfrag load_frag(const KParams& P, int fid, int l){
  union { uint4 q; bfrag v; } X;
  if (WS) X.q = ((const uint4*)P.ws)[fid*64 + l];
  else {
    X.q.x = pack2(frag_elem(P,fid,l,0), frag_elem(P,fid,l,1));
    X.q.y = pack2(frag_elem(P,fid,l,2), frag_elem(P,fid,l,3));
    X.q.z = pack2(frag_elem(P,fid,l,4), frag_elem(P,fid,l,5));
    X.q.w = pack2(frag_elem(P,fid,l,6), frag_elem(P,fid,l,7));
  }
  return X.v;
}
template<int WS>
__device__ __forceinline__ vf4 load_chunk(const KParams& P, int cid, int l){
  vf4 r;
  if (WS){
    float4 t = ((const float4*)(P.ws + 16384))[cid*64 + l];
    r[0]=t.x; r[1]=t.y; r[2]=t.z; r[3]=t.w;
  } else {
    r[0]=chunk_elem(P,cid,l,0); r[1]=chunk_elem(P,cid,l,1);
    r[2]=chunk_elem(P,cid,l,2); r[3]=chunk_elem(P,cid,l,3);
  }
  return r;
}

// Two D-chunks (relu optional) -> one B-frag of the next layer (zero cross-lane moves)
template<bool RELU>
__device__ __forceinline__ bfrag packAB(vf4 A, vf4 B){
  if (RELU){
    #pragma unroll
    for (int i=0;i<4;i++){ A[i]=fmaxf(A[i],0.f); B[i]=fmaxf(B[i],0.f); }
  }
  union { unsigned u[4]; bfrag v; } X;
  X.u[0]=pack2(A[0],A[1]); X.u[1]=pack2(A[2],A[3]);
  X.u[2]=pack2(B[0],B[1]); X.u[3]=pack2(B[2],B[3]);
  return X.v;
}

template<int WS>
__global__ __launch_bounds__(256,2) void fused_policy(KParams P){
  __shared__ float lds_v [4][16][64];   // v_contrib (task part of value head)
  __shared__ float lds_sc[4][16][33];   // scores (33 == 1 mod 32 -> conflict-free)
  __shared__ float lds_pr[4][16][33];   // unnormalized exp
  __shared__ float lds_inv[4][16];
  const int tid = threadIdx.x;
  const int wid = tid>>6, l = tid&63, col = l&15, grp = l>>4;
  const int b0  = (blockIdx.x*4 + wid)*16;           // 16 samples per wave
  const vf4 Z = {0.f,0.f,0.f,0.f};

  // ---------- task phase (per-b, amortized over 32 n) ----------
  const float* tp = P.task + (size_t)(b0+col)*17;
  union { unsigned u[4]; bfrag v; } TB;
  TB.u[0]=pack2(tp[grp*4+0],tp[grp*4+1]);
  TB.u[1]=pack2(tp[grp*4+2],tp[grp*4+3]);
  TB.u[2]= (grp==0) ? pack2(tp[16], 1.f) : 0u;   // feature 16 + bias-1.0 at k=17
  TB.u[3]=0u;
  vf4 a1[4];
  #pragma unroll
  for (int c=0;c<4;c++) a1[c] = MFMA16(load_frag<WS>(P,c,l), TB.v, Z);
  bfrag h1B0 = packAB<true>(a1[0],a1[1]), h1B1 = packAB<true>(a1[2],a1[3]);
  vf4 a2[4];
  #pragma unroll
  for (int c=0;c<4;c++){
    a2[c] = MFMA16(load_frag<WS>(P,4+2*c,l), h1B0, load_chunk<WS>(P,c,l));
    a2[c] = MFMA16(load_frag<WS>(P,5+2*c,l), h1B1, a2[c]);
  }
  bfrag teB0 = packAB<true>(a2[0],a2[1]), teB1 = packAB<true>(a2[2],a2[3]);
  vf4 tc[4];                                   // t_contrib = task_emb@sc_w1[0:64]+sc_b1
  #pragma unroll
  for (int c=0;c<4;c++){
    tc[c] = MFMA16(load_frag<WS>(P,12+2*c,l), teB0, load_chunk<WS>(P,4+c,l));
    tc[c] = MFMA16(load_frag<WS>(P,13+2*c,l), teB1, tc[c]);
  }
  #pragma unroll
  for (int c=0;c<4;c++){                       // v_contrib -> LDS (used once at end)
    vf4 vc = MFMA16(load_frag<WS>(P,20+2*c,l), teB0, load_chunk<WS>(P,8+c,l));
    vc = MFMA16(load_frag<WS>(P,21+2*c,l), teB1, vc);
    *(float4*)&lds_v[wid][col][c*16+grp*4] = make_float4(vc[0],vc[1],vc[2],vc[3]);
  }
  float rpart = 0.f;                           // reject head
  #pragma unroll
  for (int c=0;c<2;c++){
    vf4 rv = MFMA16(load_frag<WS>(P,28+2*c,l), teB0, load_chunk<WS>(P,12+c,l));
    rv = MFMA16(load_frag<WS>(P,29+2*c,l), teB1, rv);
    vf4 w2 = load_chunk<WS>(P,22+c,l);
    #pragma unroll
    for (int r=0;r<4;r++) rpart += fmaxf(rv[r],0.f)*w2[r];
  }
  rpart += __shfl_xor(rpart,16);
  rpart += __shfl_xor(rpart,32);
  const float reject = rpart + P.rj_b2[0];

  // ---------- resident main-loop weights ----------
  bfrag Fhe1[4], Fhe2[8], Fs1[8], Fs2[4];
  #pragma unroll
  for (int i=0;i<4;i++) Fhe1[i]=load_frag<WS>(P,32+i,l);
  #pragma unroll
  for (int i=0;i<8;i++) Fhe2[i]=load_frag<WS>(P,36+i,l);
  #pragma unroll
  for (int i=0;i<8;i++) Fs1[i]=load_frag<WS>(P,44+i,l);
  #pragma unroll
  for (int i=0;i<4;i++) Fs2[i]=load_frag<WS>(P,52+i,l);
  vf4 Bhe2[4], Bsc2[2], W3[2];
  #pragma unroll
  for (int c=0;c<4;c++) Bhe2[c]=load_chunk<WS>(P,14+c,l);
  #pragma unroll
  for (int c=0;c<2;c++) Bsc2[c]=load_chunk<WS>(P,18+c,l);
  #pragma unroll
  for (int c=0;c<2;c++) W3[c]=load_chunk<WS>(P,20+c,l);
  const float scb3 = P.sc_b3[0];
  vf4 macc[4];
  #pragma unroll
  for (int c=0;c<4;c++) macc[c]=Z;

  // ---------- main loop over n (one 16-sample tile per iter) ----------
  const float* hwp = P.hw + (size_t)(b0+col)*512 + grp*4;
  float4 hv = *(const float4*)hwp;
  #pragma unroll 1
  for (int n=0;n<32;n++){
    float4 hv_next = hv;
    if (n < 31) hv_next = *(const float4*)(hwp + (n+1)*16);   // prefetch
    union { unsigned u[4]; bfrag v; } HB;
    HB.u[0]=pack2(hv.x,hv.y); HB.u[1]=pack2(hv.z,hv.w);
    HB.u[2]= (grp==0) ? pack2(1.f,0.f) : 0u;                  // bias-1.0 at k=16
    HB.u[3]=0u;
    vf4 g1[4];
    #pragma unroll
    for (int c=0;c<4;c++) g1[c]=MFMA16(Fhe1[c], HB.v, Z);
    bfrag g1B0 = packAB<true>(g1[0],g1[1]), g1B1 = packAB<true>(g1[2],g1[3]);
    vf4 g2[4];
    #pragma unroll
    for (int c=0;c<4;c++){
      g2[c]=MFMA16(Fhe2[2*c],   g1B0, Bhe2[c]);
      g2[c]=MFMA16(Fhe2[2*c+1], g1B1, g2[c]);
      #pragma unroll
      for (int r=0;r<4;r++){ g2[c][r]=fmaxf(g2[c][r],0.f); macc[c][r]+=g2[c][r]; }
    }
    bfrag g2B0 = packAB<false>(g2[0],g2[1]), g2B1 = packAB<false>(g2[2],g2[3]);
    vf4 s1[4];
    #pragma unroll
    for (int c=0;c<4;c++){
      s1[c]=MFMA16(Fs1[2*c],   g2B0, tc[c]);      // C-init = task contribution
      s1[c]=MFMA16(Fs1[2*c+1], g2B1, s1[c]);
    }
    bfrag s1B0 = packAB<true>(s1[0],s1[1]), s1B1 = packAB<true>(s1[2],s1[3]);
    float sp = 0.f;
    #pragma unroll
    for (int c=0;c<2;c++){
      vf4 s2 = MFMA16(Fs2[2*c],   s1B0, Bsc2[c]);
      s2     = MFMA16(Fs2[2*c+1], s1B1, s2);
      #pragma unroll
      for (int r=0;r<4;r++) sp += fmaxf(s2[r],0.f)*W3[c][r];
    }
    sp += __shfl_xor(sp,16);
    sp += __shfl_xor(sp,32);
    if (l<16) lds_sc[wid][l][n] = sp + scb3;
    hv = hv_next;
  }
  if (l<16) lds_sc[wid][l][32] = reject;

  // ---------- value head ----------
  #pragma unroll
  for (int c=0;c<4;c++){
    #pragma unroll
    for (int r=0;r<4;r++) macc[c][r] *= (1.f/32.f);
  }
  bfrag mB0 = packAB<false>(macc[0],macc[1]), mB1 = packAB<false>(macc[2],macc[3]);
  asm volatile("s_waitcnt lgkmcnt(0)" ::: "memory");
  float vpart = 0.f;
  #pragma unroll
  for (int c=0;c<4;c++){
    float4 ci4 = *(const float4*)&lds_v[wid][col][c*16+grp*4];
    vf4 ci = {ci4.x,ci4.y,ci4.z,ci4.w};
    vf4 vD = MFMA16(load_frag<WS>(P,56+2*c,l), mB0, ci);
    vD     = MFMA16(load_frag<WS>(P,57+2*c,l), mB1, vD);
    vf4 w2 = load_chunk<WS>(P,24+c,l);
    #pragma unroll
    for (int r=0;r<4;r++) vpart += fmaxf(vD[r],0.f)*w2[r];
  }
  vpart += __shfl_xor(vpart,16);
  vpart += __shfl_xor(vpart,32);
  if (l<16) P.out[(size_t)P.B*33 + b0 + l] = vpart + P.vh_b2[0];

  // ---------- softmax (lanes 0-15, one sample each) ----------
  asm volatile("s_waitcnt lgkmcnt(0)" ::: "memory");
  if (l<16){
    float s[33];
    #pragma unroll
    for (int j=0;j<32;j++) s[j]=lds_sc[wid][l][j];
    s[32]=reject;
    // valid_mask is bool in the reference -> int32 on the harness side (32 ints/sample)
    const int4* mp = (const int4*)(P.mask + (size_t)(b0+l)*32);
    #pragma unroll
    for (int w=0;w<8;w++){
      int4 m4 = mp[w];
      if (m4.x==0) s[w*4+0] = -INFINITY;
      if (m4.y==0) s[w*4+1] = -INFINITY;
      if (m4.z==0) s[w*4+2] = -INFINITY;
      if (m4.w==0) s[w*4+3] = -INFINITY;
    }
    #pragma unroll
    for (int j=0;j<32;j++) lds_sc[wid][l][j] = s[j];   // masked scores for output
    float mx = s[32];
    #pragma unroll
    for (int j=0;j<32;j++) mx = fmaxf(mx, s[j]);
    float sum = 0.f;
    #pragma unroll
    for (int j=0;j<33;j++){
      float p = __expf(s[j]-mx); sum += p; lds_pr[wid][l][j] = p;
    }
    lds_inv[wid][l] = 1.f/sum;
  }
  asm volatile("s_waitcnt lgkmcnt(0)" ::: "memory");
  const float* prf = &lds_pr[wid][0][0];
  const float* scf = &lds_sc[wid][0][0];
  #pragma unroll 1
  for (int i=l; i<528; i+=64){                       // coalesced flush: 16*33 floats
    unsigned bl = (unsigned)i/33u;
    P.out[(size_t)b0*33 + i]                      = prf[i]*lds_inv[wid][bl];
    P.out[(size_t)P.B*34 + (size_t)b0*33 + i]     = scf[i];
  }
}

extern "C" void kernel_launch(void* const* d_in, const int* in_sizes, int n_in,
                              void* d_out, int out_size, void* d_ws, size_t ws_size,
                              hipStream_t stream){
  KParams P;
  P.task  = (const float*)d_in[0];
  P.hw    = (const float*)d_in[1];
  P.mask  = (const int*)d_in[2];
  P.te_w1 = (const float*)d_in[3];  P.te_b1 = (const float*)d_in[4];
  P.te_w2 = (const float*)d_in[5];  P.te_b2 = (const float*)d_in[6];
  P.he_w1 = (const float*)d_in[7];  P.he_b1 = (const float*)d_in[8];
  P.he_w2 = (const float*)d_in[9];  P.he_b2 = (const float*)d_in[10];
  P.sc_w1 = (const float*)d_in[11]; P.sc_b1 = (const float*)d_in[12];
  P.sc_w2 = (const float*)d_in[13]; P.sc_b2 = (const float*)d_in[14];
  P.sc_w3 = (const float*)d_in[15]; P.sc_b3 = (const float*)d_in[16];
  P.rj_w1 = (const float*)d_in[17]; P.rj_b1 = (const float*)d_in[18];
  P.rj_w2 = (const float*)d_in[19]; P.rj_b2 = (const float*)d_in[20];
  P.vh_w1 = (const float*)d_in[21]; P.vh_b1 = (const float*)d_in[22];
  P.vh_w2 = (const float*)d_in[23]; P.vh_b2 = (const float*)d_in[24];
  P.out = (float*)d_out;
  P.ws  = (float*)d_ws;
  P.B   = in_sizes[0] / 17;
  const size_t need = 64u*1024u + 28u*1024u;     // frag + chunk regions
  const bool use_ws = (d_ws != nullptr) && (ws_size >= need);
  if (use_ws){
    setup_frags<<<92, 64, 0, stream>>>(P);
    fused_policy<1><<<P.B/64, 256, 0, stream>>>(P);
  } else {
    fused_policy<0><<<P.B/64, 256, 0, stream>>>(P);
  }
}